// Round 4
// baseline (280.151 us; speedup 1.0000x reference)
//
#include <hip/hip_runtime.h>
#include <math.h>

#define NORB 13
#define NORB2 (NORB * NORB)
#define GB 16                       // b-blocks per workgroup (16*104B = 13 lines)

// block id per orbital index for L_LIST=[0,0,1,1,2] -> sizes 1,1,3,3,5
__device__ __forceinline__ int blk_of(int p) {
    return p < 1 ? 0 : (p < 2 ? 1 : (p < 5 ? 2 : (p < 8 ? 3 : 4)));
}
__device__ __forceinline__ float ffac(int p, int q) {
    int bp = blk_of(p), bq = blk_of(q);
    return bp < bq ? 1.0f : (bp == bq ? 0.5f : 0.0f);
}

// ---------------- CSR build over destination blocks (validated round 3) ------
__global__ void k_ws_zero(int* __restrict__ cnt, int nbins) {
    int i = blockIdx.x * blockDim.x + threadIdx.x;
    if (i < nbins) cnt[i] = 0;
}

__global__ void k_count(const int* __restrict__ edge_index, int* __restrict__ cnt,
                        int E, int N) {
    int e = blockIdx.x * blockDim.x + threadIdx.x;
    if (e >= E) return;
    int ie = edge_index[e], je = edge_index[E + e];
    atomicAdd(cnt + ie * N + je, 1);
    atomicAdd(cnt + je * N + ie, 1);
}

__global__ void k_scan(const int* __restrict__ cnt, int* __restrict__ rowptr,
                       int* __restrict__ cursor, int nbins) {
    __shared__ int part[257];
    int tid = threadIdx.x;
    int per = nbins / 256;
    int base = tid * per;
    int s = 0;
    for (int i = 0; i < per; ++i) s += cnt[base + i];
    part[tid + 1] = s;
    __syncthreads();
    if (tid == 0) {
        part[0] = 0;
        for (int i = 1; i <= 256; ++i) part[i] += part[i - 1];
    }
    __syncthreads();
    int run = part[tid];
    for (int i = 0; i < per; ++i) {
        rowptr[base + i] = run;
        cursor[base + i] = run;
        run += cnt[base + i];
    }
    if (tid == 255) rowptr[nbins] = run;
}

__global__ void k_fill(const int* __restrict__ edge_index, int* __restrict__ cursor,
                       int* __restrict__ entries, int E, int N) {
    int e = blockIdx.x * blockDim.x + threadIdx.x;
    if (e >= E) return;
    int ie = edge_index[e], je = edge_index[E + e];
    int pos = atomicAdd(cursor + ie * N + je, 1);
    entries[pos] = (e << 1);           // forward: phase * hopF
    pos = atomicAdd(cursor + je * N + ie, 1);
    entries[pos] = (e << 1) | 1;       // reverse: conj(phase) * hopF^T
}

// ---------------- fused assemble: one WG per (k, a, 16-b-group) --------------
// Accumulates a 13 x (16*13) complex region in LDS, then streams it out as
// 128B-aligned float4 stores. Every output byte written exactly once; no
// atomics; no cache-line sharing between WGs.
__global__ void __launch_bounds__(256)
k_assemble(const float* __restrict__ hopping,
           const float* __restrict__ onsite,
           const float* __restrict__ kpoints,
           const float* __restrict__ cell_shift,
           const int* __restrict__ rowptr,
           const int* __restrict__ entries,
           float* __restrict__ out,
           int N, int K, int ld, int es, int ngroups) {
    int g = blockIdx.x % ngroups;
    int a = (blockIdx.x / ngroups) % N;
    int k = blockIdx.x / (ngroups * N);
    int tid = threadIdx.x;
    int b0 = g * GB;
    int nb = min(GB, N - b0);

    // [row p][b-in-group i][col q][re/im]; row stride = GB*NORB*2 = 416 floats
    __shared__ __align__(16) float lds[NORB * GB * NORB * 2];   // 21632 B

    const int LDSF = NORB * GB * NORB * 2;      // 5408 floats
    for (int i = tid; i < LDSF; i += 256) lds[i] = 0.f;
    __syncthreads();

    int p = 0, q = 0;
    bool act = tid < NORB2;
    if (act) { p = tid / NORB; q = tid - p * NORB; }
    float fpq = act ? ffac(p, q) : 0.f;
    float fqp = act ? ffac(q, p) : 0.f;

    // onsite hermitized term on the diagonal block (if it falls in this group)
    if (a >= b0 && a < b0 + nb && act) {
        const float* on = onsite + (size_t)a * NORB2;
        float v = on[p * NORB + q] * fpq + on[q * NORB + p] * fqp;
        lds[(p * GB * NORB + (a - b0) * NORB + q) * 2] = v;
    }

    float kx = kpoints[3 * k], ky = kpoints[3 * k + 1], kz = kpoints[3 * k + 2];

    for (int i = 0; i < nb; ++i) {
        int bin = a * N + b0 + i;
        int beg = rowptr[bin], end = rowptr[bin + 1];
        for (int it = beg; it < end; ++it) {
            int ent = entries[it];               // uniform across WG
            int e = ent >> 1, rev = ent & 1;
            float Rx = cell_shift[3 * e], Ry = cell_shift[3 * e + 1], Rz = cell_shift[3 * e + 2];
            float d = kx * Rx + ky * Ry + kz * Rz;
            float s, c;
            sincosf(-6.2831853071795864f * d, &s, &c);  // exp(-i*2pi*d) = c + i*s
            float im = rev ? -s : s;                    // conj for reverse
            if (act) {
                const float* h = hopping + (size_t)e * NORB2;
                float hv = rev ? h[q * NORB + p] * fqp : h[p * NORB + q] * fpq;
                int base = (p * GB * NORB + i * NORB + q) * 2;
                lds[base]     += c * hv;
                lds[base + 1] += im * hv;
            }
        }
    }
    __syncthreads();

    // ---- store LDS region to global ----
    if (es == 2 && nb == GB) {
        // full group: rows are 1664B contiguous, 128B-aligned -> float4 stream
        const int ROWF4 = GB * NORB * 2 / 4;    // 104 float4 per row
        const float4* l4 = (const float4*)lds;
        float4* o4 = (float4*)out;
        for (int idx = tid; idx < NORB * ROWF4; idx += 256) {
            int row = idx / ROWF4;
            int col = idx - row * ROWF4;
            size_t gc = ((size_t)k * ld + (size_t)a * NORB + row) * ld + (size_t)b0 * NORB;
            o4[(gc >> 1) + col] = l4[row * ROWF4 + col];   // gc even (b0 mult of 16)
        }
    } else if (es == 2) {
        // partial tail group: float2 per element
        float2* o2 = (float2*)out;
        int nelem = NORB * nb * NORB;
        for (int idx = tid; idx < nelem; idx += 256) {
            int row = idx / (nb * NORB);
            int rem = idx - row * nb * NORB;
            size_t gc = ((size_t)k * ld + (size_t)a * NORB + row) * ld + (size_t)b0 * NORB + rem;
            int li = (row * GB * NORB + rem) * 2;
            o2[gc] = make_float2(lds[li], lds[li + 1]);
        }
    } else {
        // real-only layout fallback
        int nelem = NORB * nb * NORB;
        for (int idx = tid; idx < nelem; idx += 256) {
            int row = idx / (nb * NORB);
            int rem = idx - row * nb * NORB;
            size_t gc = ((size_t)k * ld + (size_t)a * NORB + row) * ld + (size_t)b0 * NORB + rem;
            out[gc] = lds[(row * GB * NORB + rem) * 2];
        }
    }
}

extern "C" void kernel_launch(void* const* d_in, const int* in_sizes, int n_in,
                              void* d_out, int out_size, void* d_ws, size_t ws_size,
                              hipStream_t stream) {
    const float* hopping    = (const float*)d_in[0];
    const float* onsite     = (const float*)d_in[1];
    const float* kpoints    = (const float*)d_in[2];
    const float* cell_shift = (const float*)d_in[3];
    const int*   edge_index = (const int*)d_in[4];
    float* out = (float*)d_out;

    int E = in_sizes[0] / NORB2;   // 2048
    int N = in_sizes[1] / NORB2;   // 128
    int K = in_sizes[2] / 3;       // 16
    int ld = N * NORB;             // 1664
    int nbins = N * N;             // 16384

    size_t full = (size_t)K * ld * ld * 2;
    int es = ((size_t)out_size >= full) ? 2 : 1;

    // workspace (ints): cnt[nbins], rowptr[nbins+1], cursor[nbins], entries[2E]
    int* cnt     = (int*)d_ws;
    int* rowptr  = cnt + nbins;
    int* cursor  = rowptr + nbins + 1;
    int* entries = cursor + nbins;

    k_ws_zero<<<(nbins + 255) / 256, 256, 0, stream>>>(cnt, nbins);
    k_count  <<<(E + 255) / 256, 256, 0, stream>>>(edge_index, cnt, E, N);
    k_scan   <<<1, 256, 0, stream>>>(cnt, rowptr, cursor, nbins);
    k_fill   <<<(E + 255) / 256, 256, 0, stream>>>(edge_index, cursor, entries, E, N);

    int ngroups = (N + GB - 1) / GB;            // 8
    int nwg = K * N * ngroups;                  // 16384
    k_assemble<<<nwg, 256, 0, stream>>>(hopping, onsite, kpoints, cell_shift,
                                        rowptr, entries, out, N, K, ld, es, ngroups);
}

// Round 6
// 232.935 us; speedup vs baseline: 1.2027x; 1.2027x over previous
//
#include <hip/hip_runtime.h>
#include <math.h>

#define NORB 13
#define NORB2 (NORB * NORB)
#define GB 16                       // b-blocks per group (16*104B = 13 cache lines)

typedef float fx4 __attribute__((ext_vector_type(4)));   // clang-native float4

// block id per orbital index for L_LIST=[0,0,1,1,2] -> sizes 1,1,3,3,5
__device__ __forceinline__ int blk_of(int p) {
    return p < 1 ? 0 : (p < 2 ? 1 : (p < 5 ? 2 : (p < 8 ? 3 : 4)));
}
__device__ __forceinline__ float ffac(int p, int q) {
    int bp = blk_of(p), bq = blk_of(q);
    return bp < bq ? 1.0f : (bp == bq ? 0.5f : 0.0f);
}

// ---- single-WG CSR build over (a, b-group) bins ----------------------------
// bins: bin = a*ngroups + (b>>4); entry = (e<<9) | (rev<<8) | col_atom
__global__ void __launch_bounds__(256)
k_build(const int* __restrict__ edge_index, int* __restrict__ rowptr,
        int* __restrict__ entries, int E, int N, int ngroups) {
    extern __shared__ int sm[];            // cnt[nbins] + cursor[nbins] + part[257]
    int nbins = N * ngroups;
    int* cnt    = sm;
    int* cursor = sm + nbins;
    int* part   = sm + 2 * nbins;
    int tid = threadIdx.x;

    for (int i = tid; i < nbins; i += 256) cnt[i] = 0;
    __syncthreads();

    for (int e = tid; e < E; e += 256) {
        int ie = edge_index[e], je = edge_index[E + e];
        atomicAdd(cnt + ie * ngroups + (je >> 4), 1);   // forward into (ie, je)
        atomicAdd(cnt + je * ngroups + (ie >> 4), 1);   // reverse into (je, ie)
    }
    __syncthreads();

    // hierarchical exclusive scan over nbins (nbins multiple of 256)
    int per = nbins / 256;
    int base = tid * per;
    int s = 0;
    for (int i = 0; i < per; ++i) s += cnt[base + i];
    part[tid + 1] = s;
    __syncthreads();
    if (tid == 0) {
        part[0] = 0;
        for (int i = 1; i <= 256; ++i) part[i] += part[i - 1];
    }
    __syncthreads();
    int run = part[tid];
    for (int i = 0; i < per; ++i) {
        rowptr[base + i] = run;
        cursor[base + i] = run;
        run += cnt[base + i];
    }
    if (tid == 255) rowptr[nbins] = run;
    __syncthreads();

    for (int e = tid; e < E; e += 256) {
        int ie = edge_index[e], je = edge_index[E + e];
        int pos = atomicAdd(cursor + ie * ngroups + (je >> 4), 1);
        entries[pos] = (e << 9) | je;                   // forward: phase * hopF
        pos = atomicAdd(cursor + je * ngroups + (ie >> 4), 1);
        entries[pos] = (e << 9) | 256 | ie;             // reverse: conj * hopF^T
    }
}

// ---- fused assemble: one WG per (k, a, b-group) ----------------------------
// LDS-accumulate the 13 x (16*13) complex strip, then stream it out as
// full-line, 128B-aligned, non-temporal float4 stores. One rowptr pair per WG.
__global__ void __launch_bounds__(256)
k_assemble(const float* __restrict__ hopping,
           const float* __restrict__ onsite,
           const float* __restrict__ kpoints,
           const float* __restrict__ cell_shift,
           const int* __restrict__ rowptr,
           const int* __restrict__ entries,
           float* __restrict__ out,
           int N, int K, int ld, int es, int ngroups) {
    int g = blockIdx.x % ngroups;
    int a = (blockIdx.x / ngroups) % N;
    int k = blockIdx.x / (ngroups * N);
    int tid = threadIdx.x;
    int b0 = g * GB;
    int nb = min(GB, N - b0);

    // [row p][b-in-group i][col q][re/im]; 5408 floats = 21632 B
    __shared__ __align__(16) float lds[NORB * GB * NORB * 2];
    fx4* lds4 = (fx4*)lds;
    const int LDSF4 = NORB * GB * NORB * 2 / 4;      // 1352
    for (int i = tid; i < LDSF4; i += 256)
        lds4[i] = (fx4){0.f, 0.f, 0.f, 0.f};

    int p = 0, q = 0;
    bool act = tid < NORB2;
    if (act) { p = tid / NORB; q = tid - p * NORB; }
    float fpq = act ? ffac(p, q) : 0.f;
    float fqp = act ? ffac(q, p) : 0.f;
    float kx = kpoints[3 * k], ky = kpoints[3 * k + 1], kz = kpoints[3 * k + 2];

    int bin = a * ngroups + g;
    int beg = rowptr[bin], end = rowptr[bin + 1];
    __syncthreads();

    // onsite hermitized term on the diagonal block (if in this group)
    if (a >= b0 && a < b0 + nb && act) {
        const float* on = onsite + (size_t)a * NORB2;
        float v = on[p * NORB + q] * fpq + on[q * NORB + p] * fqp;
        lds[(p * GB * NORB + (a - b0) * NORB + q) * 2] = v;
    }

    for (int it = beg; it < end; ++it) {
        int ent = entries[it];                       // uniform across WG
        int e = ent >> 9;
        int rev = ent & 256;
        int i = (ent & 255) - b0;                    // b-slot within group
        float Rx = cell_shift[3 * e], Ry = cell_shift[3 * e + 1], Rz = cell_shift[3 * e + 2];
        float d = kx * Rx + ky * Ry + kz * Rz;
        float s, c;
        sincosf(-6.2831853071795864f * d, &s, &c);   // exp(-i*2pi*d) = c + i*s
        float im = rev ? -s : s;                     // conj for reverse direction
        if (act) {
            const float* h = hopping + (size_t)e * NORB2;
            float hv = rev ? h[q * NORB + p] * fqp : h[p * NORB + q] * fpq;
            int base = (p * GB * NORB + i * NORB + q) * 2;
            lds[base]     += c * hv;
            lds[base + 1] += im * hv;
        }
    }
    __syncthreads();

    // ---- store LDS strip to global ----
    if (es == 2 && nb == GB) {
        const int ROWF4 = GB * NORB * 2 / 4;         // 104 fx4 per row
        fx4* o4 = (fx4*)out;
        for (int idx = tid; idx < NORB * ROWF4; idx += 256) {
            int row = idx / ROWF4;
            int col = idx - row * ROWF4;
            size_t gc = ((size_t)k * ld + (size_t)a * NORB + row) * ld + (size_t)b0 * NORB;
            __builtin_nontemporal_store(lds4[row * ROWF4 + col], &o4[(gc >> 1) + col]);
        }
    } else if (es == 2) {
        float2* o2 = (float2*)out;
        int nelem = NORB * nb * NORB;
        for (int idx = tid; idx < nelem; idx += 256) {
            int row = idx / (nb * NORB);
            int rem = idx - row * nb * NORB;
            size_t gc = ((size_t)k * ld + (size_t)a * NORB + row) * ld + (size_t)b0 * NORB + rem;
            int li = (row * GB * NORB + rem) * 2;
            o2[gc] = make_float2(lds[li], lds[li + 1]);
        }
    } else {
        int nelem = NORB * nb * NORB;
        for (int idx = tid; idx < nelem; idx += 256) {
            int row = idx / (nb * NORB);
            int rem = idx - row * nb * NORB;
            size_t gc = ((size_t)k * ld + (size_t)a * NORB + row) * ld + (size_t)b0 * NORB + rem;
            out[gc] = lds[(row * GB * NORB + rem) * 2];
        }
    }
}

extern "C" void kernel_launch(void* const* d_in, const int* in_sizes, int n_in,
                              void* d_out, int out_size, void* d_ws, size_t ws_size,
                              hipStream_t stream) {
    const float* hopping    = (const float*)d_in[0];
    const float* onsite     = (const float*)d_in[1];
    const float* kpoints    = (const float*)d_in[2];
    const float* cell_shift = (const float*)d_in[3];
    const int*   edge_index = (const int*)d_in[4];
    float* out = (float*)d_out;

    int E = in_sizes[0] / NORB2;   // 2048
    int N = in_sizes[1] / NORB2;   // 128
    int K = in_sizes[2] / 3;       // 16
    int ld = N * NORB;             // 1664
    int ngroups = (N + GB - 1) / GB;   // 8
    int nbins = N * ngroups;           // 1024

    size_t full = (size_t)K * ld * ld * 2;
    int es = ((size_t)out_size >= full) ? 2 : 1;

    // workspace (ints): rowptr[nbins+1], entries[2E]  (~20 KB)
    int* rowptr  = (int*)d_ws;
    int* entries = rowptr + nbins + 1;

    // one-WG CSR build: LDS = cnt[nbins] + cursor[nbins] + part[257]
    size_t build_lds = (size_t)(2 * nbins + 257) * sizeof(int);
    k_build<<<1, 256, build_lds, stream>>>(edge_index, rowptr, entries, E, N, ngroups);

    int nwg = K * N * ngroups;                  // 16384
    k_assemble<<<nwg, 256, 0, stream>>>(hopping, onsite, kpoints, cell_shift,
                                        rowptr, entries, out, N, K, ld, es, ngroups);
}

// Round 7
// 223.828 us; speedup vs baseline: 1.2516x; 1.0407x over previous
//
#include <hip/hip_runtime.h>
#include <math.h>

#define NORB 13
#define NORB2 (NORB * NORB)
#define GB 16                       // b-blocks per group (16*104B = 13 cache lines)
#define KSPLIT 2                    // k-chunks per (a,group) strip

typedef float fx4 __attribute__((ext_vector_type(4)));   // clang-native float4

// block id per orbital index for L_LIST=[0,0,1,1,2] -> sizes 1,1,3,3,5
__device__ __forceinline__ int blk_of(int p) {
    return p < 1 ? 0 : (p < 2 ? 1 : (p < 5 ? 2 : (p < 8 ? 3 : 4)));
}
__device__ __forceinline__ float ffac(int p, int q) {
    int bp = blk_of(p), bq = blk_of(q);
    return bp < bq ? 1.0f : (bp == bq ? 0.5f : 0.0f);
}

// ---- single-WG CSR build over (a, b-group) bins (validated round 6) --------
__global__ void __launch_bounds__(256)
k_build(const int* __restrict__ edge_index, int* __restrict__ rowptr,
        int* __restrict__ entries, int E, int N, int ngroups) {
    extern __shared__ int sm[];            // cnt[nbins] + cursor[nbins] + part[257]
    int nbins = N * ngroups;
    int* cnt    = sm;
    int* cursor = sm + nbins;
    int* part   = sm + 2 * nbins;
    int tid = threadIdx.x;

    for (int i = tid; i < nbins; i += 256) cnt[i] = 0;
    __syncthreads();

    for (int e = tid; e < E; e += 256) {
        int ie = edge_index[e], je = edge_index[E + e];
        atomicAdd(cnt + ie * ngroups + (je >> 4), 1);
        atomicAdd(cnt + je * ngroups + (ie >> 4), 1);
    }
    __syncthreads();

    int per = nbins / 256;
    int base = tid * per;
    int s = 0;
    for (int i = 0; i < per; ++i) s += cnt[base + i];
    part[tid + 1] = s;
    __syncthreads();
    if (tid == 0) {
        part[0] = 0;
        for (int i = 1; i <= 256; ++i) part[i] += part[i - 1];
    }
    __syncthreads();
    int run = part[tid];
    for (int i = 0; i < per; ++i) {
        rowptr[base + i] = run;
        cursor[base + i] = run;
        run += cnt[base + i];
    }
    if (tid == 255) rowptr[nbins] = run;
    __syncthreads();

    for (int e = tid; e < E; e += 256) {
        int ie = edge_index[e], je = edge_index[E + e];
        int pos = atomicAdd(cursor + ie * ngroups + (je >> 4), 1);
        entries[pos] = (e << 9) | je;                   // forward: phase * hopF
        pos = atomicAdd(cursor + je * ngroups + (ie >> 4), 1);
        entries[pos] = (e << 9) | 256 | ie;             // reverse: conj * hopF^T
    }
}

// ---- fused assemble: one WG per (a, b-group, k-chunk) ----------------------
// Loops K/KSPLIT k-values over one CSR bin; per k: accumulate into LDS strip,
// then store+re-zero in one pass (full-line 128B-aligned float4 stores).
__global__ void __launch_bounds__(256)
k_assemble(const float* __restrict__ hopping,
           const float* __restrict__ onsite,
           const float* __restrict__ kpoints,
           const float* __restrict__ cell_shift,
           const int* __restrict__ rowptr,
           const int* __restrict__ entries,
           float* __restrict__ out,
           int N, int K, int ld, int es, int ngroups) {
    int g  = blockIdx.x % ngroups;
    int a  = (blockIdx.x / ngroups) % N;
    int kc = blockIdx.x / (ngroups * N);
    int kch = (K + KSPLIT - 1) / KSPLIT;
    int k0 = kc * kch, k1 = min(K, k0 + kch);
    int tid = threadIdx.x;
    int b0 = g * GB;
    int nb = min(GB, N - b0);

    // [row p][b-in-group i][col q][re/im]; 5408 floats = 21632 B
    __shared__ __align__(16) float lds[NORB * GB * NORB * 2];
    fx4* lds4 = (fx4*)lds;
    const int LDSF4 = NORB * GB * NORB * 2 / 4;      // 1352
    for (int i = tid; i < LDSF4; i += 256)
        lds4[i] = (fx4){0.f, 0.f, 0.f, 0.f};

    int p = 0, q = 0;
    bool act = tid < NORB2;
    if (act) { p = tid / NORB; q = tid - p * NORB; }
    float fpq = act ? ffac(p, q) : 0.f;
    float fqp = act ? ffac(q, p) : 0.f;

    // onsite hermitized value for the diagonal block (same for every k)
    bool diag = (a >= b0 && a < b0 + nb);
    float onv = 0.f;
    int  ondst = 0;
    if (diag && act) {
        const float* on = onsite + (size_t)a * NORB2;
        onv = on[p * NORB + q] * fpq + on[q * NORB + p] * fqp;
        ondst = (p * GB * NORB + (a - b0) * NORB + q) * 2;
    }

    int bin = a * ngroups + g;
    int beg = rowptr[bin], end = rowptr[bin + 1];
    __syncthreads();

    const int ROWF4 = GB * NORB * 2 / 4;             // 104 fx4 per row
    bool fastpath = (es == 2) && (nb == GB);

    for (int k = k0; k < k1; ++k) {
        float kx = kpoints[3 * k], ky = kpoints[3 * k + 1], kz = kpoints[3 * k + 2];

        // ---- accumulate ----
        if (diag && act) {
            lds[ondst] += onv;
        }
        for (int it = beg; it < end; ++it) {
            int ent = entries[it];                   // uniform across WG (L1-hot)
            int e = ent >> 9;
            int rev = ent & 256;
            int i = (ent & 255) - b0;
            float Rx = cell_shift[3 * e], Ry = cell_shift[3 * e + 1], Rz = cell_shift[3 * e + 2];
            float d = kx * Rx + ky * Ry + kz * Rz;
            float s, c;
            __sincosf(-6.2831853071795864f * d, &s, &c);  // exp(-i*2pi*d)=c+i*s
            float im = rev ? -s : s;                      // conj for reverse
            if (act) {
                const float* h = hopping + (size_t)e * NORB2;
                float hv = rev ? h[q * NORB + p] * fqp : h[p * NORB + q] * fpq;
                int base = (p * GB * NORB + i * NORB + q) * 2;
                lds[base]     += c * hv;
                lds[base + 1] += im * hv;
            }
        }
        __syncthreads();

        // ---- store strip + re-zero LDS in one pass ----
        if (fastpath) {
            fx4* o4 = (fx4*)out;
            for (int idx = tid; idx < NORB * ROWF4; idx += 256) {
                int row = idx / ROWF4;
                int col = idx - row * ROWF4;
                fx4 v = lds4[idx];
                lds4[idx] = (fx4){0.f, 0.f, 0.f, 0.f};
                size_t gc = ((size_t)k * ld + (size_t)a * NORB + row) * ld + (size_t)b0 * NORB;
                o4[(gc >> 1) + col] = v;
            }
        } else if (es == 2) {
            float2* o2 = (float2*)out;
            int nelem = NORB * nb * NORB;
            for (int idx = tid; idx < nelem; idx += 256) {
                int row = idx / (nb * NORB);
                int rem = idx - row * nb * NORB;
                size_t gc = ((size_t)k * ld + (size_t)a * NORB + row) * ld + (size_t)b0 * NORB + rem;
                int li = (row * GB * NORB + rem) * 2;
                o2[gc] = make_float2(lds[li], lds[li + 1]);
                lds[li] = 0.f; lds[li + 1] = 0.f;
            }
        } else {
            int nelem = NORB * nb * NORB;
            for (int idx = tid; idx < nelem; idx += 256) {
                int row = idx / (nb * NORB);
                int rem = idx - row * nb * NORB;
                size_t gc = ((size_t)k * ld + (size_t)a * NORB + row) * ld + (size_t)b0 * NORB + rem;
                int li = (row * GB * NORB + rem) * 2;
                out[gc] = lds[li];
                lds[li] = 0.f; lds[li + 1] = 0.f;
            }
        }
        __syncthreads();
    }
}

extern "C" void kernel_launch(void* const* d_in, const int* in_sizes, int n_in,
                              void* d_out, int out_size, void* d_ws, size_t ws_size,
                              hipStream_t stream) {
    const float* hopping    = (const float*)d_in[0];
    const float* onsite     = (const float*)d_in[1];
    const float* kpoints    = (const float*)d_in[2];
    const float* cell_shift = (const float*)d_in[3];
    const int*   edge_index = (const int*)d_in[4];
    float* out = (float*)d_out;

    int E = in_sizes[0] / NORB2;   // 2048
    int N = in_sizes[1] / NORB2;   // 128
    int K = in_sizes[2] / 3;       // 16
    int ld = N * NORB;             // 1664
    int ngroups = (N + GB - 1) / GB;   // 8
    int nbins = N * ngroups;           // 1024

    size_t full = (size_t)K * ld * ld * 2;
    int es = ((size_t)out_size >= full) ? 2 : 1;

    // workspace (ints): rowptr[nbins+1], entries[2E]  (~20 KB)
    int* rowptr  = (int*)d_ws;
    int* entries = rowptr + nbins + 1;

    size_t build_lds = (size_t)(2 * nbins + 257) * sizeof(int);
    k_build<<<1, 256, build_lds, stream>>>(edge_index, rowptr, entries, E, N, ngroups);

    int nwg = N * ngroups * KSPLIT;             // 2048
    k_assemble<<<nwg, 256, 0, stream>>>(hopping, onsite, kpoints, cell_shift,
                                        rowptr, entries, out, N, K, ld, es, ngroups);
}